// Round 6
// baseline (351.774 us; speedup 1.0000x reference)
//
#include <hip/hip_runtime.h>
#include <math.h>

#define W 4096
#define S 4096
#define NK_MAX 1024

typedef float v4f __attribute__((ext_vector_type(4)));  // clang vector — valid for nontemporal builtins

// ---------------------------------------------------------------------------
// ws layout (floats):
//   [0,     8192)  : key table float2[4096]  (cos,sin) of 2*pi*k/4096
//   [8192, 16384)  : nm    float2[4096]  (noisy_mix, interleaved re/im)
//   [16384,17408)  : corr  float[1024]
// ---------------------------------------------------------------------------
// 3-kernel chain: nm(+table) -> corr -> out(+softmax+ck).
// R3: cooperative fusion regresses (resident cap + grid syncs). Reverted.
// R4: NT cue loads are a ~25us win (keep holo L3-resident). Kept.
// R5: wave-per-row ~= block-per-row (337 vs 346) — burst-then-drain load
//     pattern caps effective read BW at ~3 TB/s regardless of shape.
// R6: depth-4 software-pipelined loads (rotation buffer, fully unrolled) so
//     12-16 loads stay in flight DURING the FMA phase, not just before it.
// ---------------------------------------------------------------------------

// Stage 0+1: noisy_mix[w] = sum_s holo[w,s]*conj(cue[w,s]).
// One WAVE per row (zero syncs). 16 steps of 1 float4/stream/lane; stages
// rotate mod 4: consume stage s&3, immediately refill it with step s+4.
__global__ __launch_bounds__(256, 4) void nm_kernel(
    const float* __restrict__ hr, const float* __restrict__ hi,
    const float* __restrict__ cr, const float* __restrict__ ci,
    float2* __restrict__ nm, float2* __restrict__ table) {
    int t = threadIdx.x;
    int lane = t & 63, wid = t >> 6;
    int bid = blockIdx.x;
    const v4f* hr4 = (const v4f*)hr;
    const v4f* hi4 = (const v4f*)hi;
    const v4f* cr4 = (const v4f*)cr;
    const v4f* ci4 = (const v4f*)ci;

    if (t < 4) {
        int k = bid * 4 + t;
        double theta = (double)k * (6.283185307179586 / (double)W);
        table[k] = make_float2((float)cos(theta), (float)sin(theta));
    }

    int w = bid * 4 + wid;                      // this wave's row
    size_t base = (size_t)w * 1024 + lane;      // float4 index of step 0

    v4f sa[4], sb[4], sc[4], sd[4];             // rotation stages
    // prologue: issue steps 0..3
#pragma unroll
    for (int p = 0; p < 4; p++) {
        size_t i = base + (size_t)p * 64;
        sa[p] = hr4[i];
        sb[p] = hi4[i];
        sc[p] = __builtin_nontemporal_load(&cr4[i]);   // cue is single-use
        sd[p] = __builtin_nontemporal_load(&ci4[i]);
    }

    v4f vr = {0.f, 0.f, 0.f, 0.f}, vi = {0.f, 0.f, 0.f, 0.f};
#pragma unroll
    for (int s = 0; s < 16; s++) {
        const int st = s & 3;                   // compile-time after unroll
        v4f a = sa[st], b = sb[st], c = sc[st], d = sd[st];
        if (s + 4 < 16) {                       // refill this stage (step s+4)
            size_t i = base + (size_t)(s + 4) * 64;
            sa[st] = hr4[i];
            sb[st] = hi4[i];
            sc[st] = __builtin_nontemporal_load(&cr4[i]);
            sd[st] = __builtin_nontemporal_load(&ci4[i]);
        }
        // (hr + i*hi)(cr - i*ci): re = hr*cr + hi*ci ; im = hi*cr - hr*ci
        vr += a * c + b * d;
        vi += b * c - a * d;
    }
    float sr = vr.x + vr.y + vr.z + vr.w;
    float si = vi.x + vi.y + vi.z + vi.w;
    for (int off = 32; off; off >>= 1) {
        sr += __shfl_down(sr, off);
        si += __shfl_down(si, off);
    }
    if (lane == 0) nm[w] = make_float2(sr, si);
}

// Stage 2: correlations[n] = |sum_w keys[n,w]*noisy_mix[w]| (no conjugation).
// One block per key; table/nm are L1/L2-hot (32 KB each).
__global__ void corr_kernel(const float2* __restrict__ nm, const float2* __restrict__ table,
                            float* __restrict__ corr, const int* __restrict__ nkp) {
    int n = blockIdx.x;
    if (n >= *nkp) return;
    int f = n + 1;
    float sr = 0.f, si = 0.f;
    for (int w = threadIdx.x; w < W; w += 256) {
        int idx = (w * f) & (W - 1);
        float2 t = table[idx];
        float2 v = nm[w];
        sr += t.x * v.x - t.y * v.y;
        si += t.x * v.y + t.y * v.x;
    }
    for (int off = 32; off; off >>= 1) {
        sr += __shfl_down(sr, off);
        si += __shfl_down(si, off);
    }
    __shared__ float s0[4], s1[4];
    int lane = threadIdx.x & 63, wid = threadIdx.x >> 6;
    if (lane == 0) { s0[wid] = sr; s1[wid] = si; }
    __syncthreads();
    if (threadIdx.x == 0) {
        float r = s0[0] + s0[1] + s0[2] + s0[3];
        float m = s1[0] + s1[1] + s1[2] + s1[3];
        corr[n] = sqrtf(r * r + m * m);
    }
}

// Stage 3+4+5: 1024 blocks. Block softmax ONCE (amortized over 4 rows, satt
// in LDS), then each wave independently computes its row's clean_key
// (ck_w = sum_n att[n] * table[(w*(n+1)) & 4095], table L1-hot) and streams
// the row with a depth-4 pipelined load loop (hr/hi are L3-hot after nm).
// NT stores: output written once, never re-read on device.
__global__ __launch_bounds__(256, 4) void out_kernel(
    const float* __restrict__ hr, const float* __restrict__ hi,
    const float* __restrict__ corr, const float2* __restrict__ table,
    const int* __restrict__ nkp, float* __restrict__ out) {
    __shared__ float satt[NK_MAX];   // unnormalized softmax weights
    __shared__ float red[8];
    int t = threadIdx.x;
    int lane = t & 63, wid = t >> 6;
    int bid = blockIdx.x;
    int nk = *nkp;
    const v4f* hr4 = (const v4f*)hr;
    const v4f* hi4 = (const v4f*)hi;

    // --- block softmax over corr[0..nk) (corr is L2-hot, 4 KB) ---
    float v[4];
    float vmax = -INFINITY;
#pragma unroll
    for (int j = 0; j < 4; j++) {
        int i = t + j * 256;
        v[j] = (i < nk) ? corr[i] * 50.0f : -INFINITY;
        vmax = fmaxf(vmax, v[j]);
    }
    for (int off = 32; off; off >>= 1) vmax = fmaxf(vmax, __shfl_down(vmax, off));
    if (lane == 0) red[wid] = vmax;
    __syncthreads();
    float M = fmaxf(fmaxf(red[0], red[1]), fmaxf(red[2], red[3]));

    float esum = 0.f;
#pragma unroll
    for (int j = 0; j < 4; j++) {
        int i = t + j * 256;
        float e = (i < nk) ? expf(v[j] - M) : 0.f;
        satt[i] = e;   // unnormalized; 0 beyond nk; divide by SUM at the end
        esum += e;
    }
    for (int off = 32; off; off >>= 1) esum += __shfl_down(esum, off);
    if (lane == 0) red[4 + wid] = esum;
    __syncthreads();   // satt + red visible
    float SUM = red[4] + red[5] + red[6] + red[7];

    // --- wave-independent from here: clean_key for this wave's row ---
    int w = bid * 4 + wid;
    size_t base = (size_t)w * 1024 + lane;
    const size_t total4 = (size_t)W * S / 4;

    float crr = 0.f, cii = 0.f;
#pragma unroll 4
    for (int k = 0; k < 16; k++) {
        int n = lane + k * 64;
        int idx = (w * (n + 1)) & (W - 1);
        float2 tt = table[idx];   // L1-hot 32 KB
        float a = satt[n];        // 0 for n >= nk
        crr += a * tt.x;
        cii += a * tt.y;
    }
    for (int off = 32; off; off >>= 1) {
        crr += __shfl_down(crr, off);
        cii += __shfl_down(cii, off);
    }
    float ckr = __shfl(crr, 0) / SUM;
    float cki = __shfl(cii, 0) / SUM;

    // --- stream the row: depth-4 pipelined loads, NT stores ---
    v4f sa[4], sb[4];
#pragma unroll
    for (int p = 0; p < 4; p++) {
        size_t i = base + (size_t)p * 64;
        sa[p] = hr4[i];
        sb[p] = hi4[i];
    }
#pragma unroll
    for (int s = 0; s < 16; s++) {
        const int st = s & 3;
        v4f a = sa[st], b = sb[st];
        if (s + 4 < 16) {
            size_t i = base + (size_t)(s + 4) * 64;
            sa[st] = hr4[i];
            sb[st] = hi4[i];
        }
        size_t i = base + (size_t)s * 64;
        v4f re = a * ckr - b * cki;
        v4f im = a * cki + b * ckr;
        __builtin_nontemporal_store(re, &((v4f*)out)[i]);
        __builtin_nontemporal_store(im, &((v4f*)out)[i + total4]);
    }
}

extern "C" void kernel_launch(void* const* d_in, const int* in_sizes, int n_in,
                              void* d_out, int out_size, void* d_ws, size_t ws_size,
                              hipStream_t stream) {
    const float* hr = (const float*)d_in[0];
    const float* hi = (const float*)d_in[1];
    const float* cr = (const float*)d_in[2];
    const float* ci = (const float*)d_in[3];
    const int* nk = (const int*)d_in[4];

    float* ws = (float*)d_ws;
    float2* table = (float2*)ws;            // [0, 8192)
    float2* nm    = (float2*)(ws + 8192);   // [8192, 16384)
    float* corr   = ws + 16384;             // [16384, 17408)
    float* out = (float*)d_out;

    nm_kernel<<<W / 4, 256, 0, stream>>>(hr, hi, cr, ci, nm, table);
    corr_kernel<<<NK_MAX, 256, 0, stream>>>(nm, table, corr, nk);
    out_kernel<<<W / 4, 256, 0, stream>>>(hr, hi, corr, table, nk, out);
}

// Round 7
// 338.181 us; speedup vs baseline: 1.0402x; 1.0402x over previous
//
#include <hip/hip_runtime.h>
#include <math.h>

#define W 4096
#define S 4096
#define NK_MAX 1024

typedef float v4f __attribute__((ext_vector_type(4)));  // clang vector — valid for nontemporal builtins

// ---------------------------------------------------------------------------
// ws layout (floats):
//   [0,     8192)  : key table float2[4096]  (cos,sin) of 2*pi*k/4096
//   [8192, 16384)  : nm    float2[4096]  (noisy_mix, interleaved re/im)
//   [16384,17408)  : corr  float[1024]
// ---------------------------------------------------------------------------
// 3-kernel chain: nm(+table) -> corr -> out(+softmax+ck).
// R3: cooperative fusion regresses (resident cap + grid syncs). Reverted.
// R4: NT-vs-plain A/B at constant bytes: NT cue loads 77us vs plain 101us.
// R5: wave-per-row, 4-chunk loads — best verified shape (<=77us nm).
// R6: deeper SW pipeline collapsed by compiler (VGPR 36 proves it); regressed.
// R7: NT on ALL streaming loads (holo too, both kernels). Model: allocating
//     reads cap ~3 TB/s (L2/L3 fill+evict churn on zero-reuse data); NT
//     bypasses allocation — the only lever that moved throughput at fixed
//     bytes. Deliberately gives up holo-in-L3 for out; NT HBM stream should
//     beat L3-hit allocating stream.
// ---------------------------------------------------------------------------

// Stage 0+1: noisy_mix[w] = sum_s holo[w,s]*conj(cue[w,s]).
// One WAVE per row (zero syncs), 4 chunks x 4 float4 per array per lane,
// shuffle-only reduce. Threads 0..3 write this block's 4 table entries
// (fp64 sincos -> exact) under the load shadow.
__global__ void nm_kernel(const float* __restrict__ hr, const float* __restrict__ hi,
                          const float* __restrict__ cr, const float* __restrict__ ci,
                          float2* __restrict__ nm, float2* __restrict__ table) {
    int t = threadIdx.x;
    int lane = t & 63, wid = t >> 6;
    int bid = blockIdx.x;
    const v4f* hr4 = (const v4f*)hr;
    const v4f* hi4 = (const v4f*)hi;
    const v4f* cr4 = (const v4f*)cr;
    const v4f* ci4 = (const v4f*)ci;

    if (t < 4) {
        int k = bid * 4 + t;
        double theta = (double)k * (6.283185307179586 / (double)W);
        table[k] = make_float2((float)cos(theta), (float)sin(theta));
    }

    int w = bid * 4 + wid;              // this wave's row
    size_t base = (size_t)w * 1024;     // 1024 float4 per row

    v4f vr = {0.f, 0.f, 0.f, 0.f}, vi = {0.f, 0.f, 0.f, 0.f};
#pragma unroll 1
    for (int ch = 0; ch < 4; ch++) {
        v4f a[4], b[4], c[4], d[4];
#pragma unroll
        for (int k = 0; k < 4; k++) {
            size_t i = base + ch * 256 + k * 64 + lane;
            a[k] = __builtin_nontemporal_load(&hr4[i]);   // all streams NT:
            b[k] = __builtin_nontemporal_load(&hi4[i]);   // zero-reuse here,
            c[k] = __builtin_nontemporal_load(&cr4[i]);   // bypass cache
            d[k] = __builtin_nontemporal_load(&ci4[i]);   // allocation churn
        }
        // (hr + i*hi)(cr - i*ci): re = hr*cr + hi*ci ; im = hi*cr - hr*ci
#pragma unroll
        for (int k = 0; k < 4; k++) {
            vr += a[k] * c[k] + b[k] * d[k];
            vi += b[k] * c[k] - a[k] * d[k];
        }
    }
    float sr = vr.x + vr.y + vr.z + vr.w;
    float si = vi.x + vi.y + vi.z + vi.w;
    for (int off = 32; off; off >>= 1) {
        sr += __shfl_down(sr, off);
        si += __shfl_down(si, off);
    }
    if (lane == 0) nm[w] = make_float2(sr, si);
}

// Stage 2: correlations[n] = |sum_w keys[n,w]*noisy_mix[w]| (no conjugation).
// One block per key; table/nm are small and reused -> normal cached loads.
__global__ void corr_kernel(const float2* __restrict__ nm, const float2* __restrict__ table,
                            float* __restrict__ corr, const int* __restrict__ nkp) {
    int n = blockIdx.x;
    if (n >= *nkp) return;
    int f = n + 1;
    float sr = 0.f, si = 0.f;
    for (int w = threadIdx.x; w < W; w += 256) {
        int idx = (w * f) & (W - 1);
        float2 t = table[idx];
        float2 v = nm[w];
        sr += t.x * v.x - t.y * v.y;
        si += t.x * v.y + t.y * v.x;
    }
    for (int off = 32; off; off >>= 1) {
        sr += __shfl_down(sr, off);
        si += __shfl_down(si, off);
    }
    __shared__ float s0[4], s1[4];
    int lane = threadIdx.x & 63, wid = threadIdx.x >> 6;
    if (lane == 0) { s0[wid] = sr; s1[wid] = si; }
    __syncthreads();
    if (threadIdx.x == 0) {
        float r = s0[0] + s0[1] + s0[2] + s0[3];
        float m = s1[0] + s1[1] + s1[2] + s1[3];
        corr[n] = sqrtf(r * r + m * m);
    }
}

// Stage 3+4+5: 1024 blocks. Block softmax ONCE (amortized over 4 rows, satt
// in LDS), then each wave independently computes its row's clean_key
// (ck_w = sum_n att[n] * table[(w*(n+1)) & 4095], table L1-hot) and streams
// the row. holo loads NT (single-use stream); NT stores (write-once output).
__global__ void out_kernel(const float* __restrict__ hr, const float* __restrict__ hi,
                           const float* __restrict__ corr, const float2* __restrict__ table,
                           const int* __restrict__ nkp, float* __restrict__ out) {
    __shared__ float satt[NK_MAX];   // unnormalized softmax weights
    __shared__ float red[8];
    int t = threadIdx.x;
    int lane = t & 63, wid = t >> 6;
    int bid = blockIdx.x;
    int nk = *nkp;
    const v4f* hr4 = (const v4f*)hr;
    const v4f* hi4 = (const v4f*)hi;

    // --- block softmax over corr[0..nk) (corr is L2-hot, 4 KB) ---
    float v[4];
    float vmax = -INFINITY;
#pragma unroll
    for (int j = 0; j < 4; j++) {
        int i = t + j * 256;
        v[j] = (i < nk) ? corr[i] * 50.0f : -INFINITY;
        vmax = fmaxf(vmax, v[j]);
    }
    for (int off = 32; off; off >>= 1) vmax = fmaxf(vmax, __shfl_down(vmax, off));
    if (lane == 0) red[wid] = vmax;
    __syncthreads();
    float M = fmaxf(fmaxf(red[0], red[1]), fmaxf(red[2], red[3]));

    float esum = 0.f;
#pragma unroll
    for (int j = 0; j < 4; j++) {
        int i = t + j * 256;
        float e = (i < nk) ? expf(v[j] - M) : 0.f;
        satt[i] = e;   // unnormalized; 0 beyond nk; divide by SUM at the end
        esum += e;
    }
    for (int off = 32; off; off >>= 1) esum += __shfl_down(esum, off);
    if (lane == 0) red[4 + wid] = esum;
    __syncthreads();   // satt + red visible
    float SUM = red[4] + red[5] + red[6] + red[7];

    // --- wave-independent from here: clean_key for this wave's row ---
    int w = bid * 4 + wid;
    size_t base = (size_t)w * 1024;
    const size_t total4 = (size_t)W * S / 4;

    float crr = 0.f, cii = 0.f;
#pragma unroll 4
    for (int k = 0; k < 16; k++) {
        int n = lane + k * 64;
        int idx = (w * (n + 1)) & (W - 1);
        float2 tt = table[idx];   // L1-hot 32 KB
        float a = satt[n];        // 0 for n >= nk
        crr += a * tt.x;
        cii += a * tt.y;
    }
    for (int off = 32; off; off >>= 1) {
        crr += __shfl_down(crr, off);
        cii += __shfl_down(cii, off);
    }
    float ckr = __shfl(crr, 0) / SUM;
    float cki = __shfl(cii, 0) / SUM;

    // --- stream the row: NT loads (single-use), NT stores (write-once) ---
#pragma unroll 1
    for (int ch = 0; ch < 4; ch++) {
        v4f a[4], b[4];
#pragma unroll
        for (int k = 0; k < 4; k++) {
            size_t i = base + ch * 256 + k * 64 + lane;
            a[k] = __builtin_nontemporal_load(&hr4[i]);
            b[k] = __builtin_nontemporal_load(&hi4[i]);
        }
#pragma unroll
        for (int k = 0; k < 4; k++) {
            size_t i = base + ch * 256 + k * 64 + lane;
            v4f re = a[k] * ckr - b[k] * cki;
            v4f im = a[k] * cki + b[k] * ckr;
            __builtin_nontemporal_store(re, &((v4f*)out)[i]);
            __builtin_nontemporal_store(im, &((v4f*)out)[i + total4]);
        }
    }
}

extern "C" void kernel_launch(void* const* d_in, const int* in_sizes, int n_in,
                              void* d_out, int out_size, void* d_ws, size_t ws_size,
                              hipStream_t stream) {
    const float* hr = (const float*)d_in[0];
    const float* hi = (const float*)d_in[1];
    const float* cr = (const float*)d_in[2];
    const float* ci = (const float*)d_in[3];
    const int* nk = (const int*)d_in[4];

    float* ws = (float*)d_ws;
    float2* table = (float2*)ws;            // [0, 8192)
    float2* nm    = (float2*)(ws + 8192);   // [8192, 16384)
    float* corr   = ws + 16384;             // [16384, 17408)
    float* out = (float*)d_out;

    nm_kernel<<<W / 4, 256, 0, stream>>>(hr, hi, cr, ci, nm, table);
    corr_kernel<<<NK_MAX, 256, 0, stream>>>(nm, table, corr, nk);
    out_kernel<<<W / 4, 256, 0, stream>>>(hr, hi, corr, table, nk, out);
}